// Round 7
// baseline (138.541 us; speedup 1.0000x reference)
//
#include <hip/hip_runtime.h>

// Problem constants (from reference setup_inputs)
#define NTOT  4096    // total nodes
#define NG    64      // graphs (B)
#define NMAXD 128     // N_MAX dense padding
#define HD    64      // hidden dim
#define NEDGE 65536   // edges (and pairs)
#define EPG   (NEDGE / NG)   // 1024 edges per graph
#define NPG   (NTOT / NG)    // 64 nodes per graph

typedef float f4 __attribute__((ext_vector_type(4)));

// ---------------------------------------------------------------------------
// prep: starts[g], pos[i] = i - starts[batch[i]], counts[g]
// ---------------------------------------------------------------------------
__global__ __launch_bounds__(1024) void prep_kernel(const int* __restrict__ batch,
                                                    int* __restrict__ starts,
                                                    int* __restrict__ pos,
                                                    int* __restrict__ counts) {
  const int tid = threadIdx.x;
  for (int i = tid; i < NTOT; i += 1024)
    if (i == 0 || batch[i] != batch[i - 1]) starts[batch[i]] = i;
  if (tid == 0) starts[NG] = NTOT;
  __syncthreads();
  for (int i = tid; i < NTOT; i += 1024) pos[i] = i - starts[batch[i]];
  if (tid < NG) counts[tid] = starts[tid + 1] - starts[tid];
}

// ---------------------------------------------------------------------------
// prep2: precompute packed (b,r,c) codes for edges, pairs, nodes.
// Removes the dependent gather chain from the hot accumulate loop.
// items: [0,NEDGE) edges, [NEDGE,2*NEDGE) pairs, [2*NEDGE, 2*NEDGE+NTOT) nodes
// ---------------------------------------------------------------------------
__global__ __launch_bounds__(256) void prep2_kernel(
    const int* __restrict__ eI, const int* __restrict__ pI,
    const int* __restrict__ batch, const int* __restrict__ pos,
    int* __restrict__ rcE, int* __restrict__ rcP, int* __restrict__ rcN) {
  const int i = blockIdx.x * 256 + threadIdx.x;
  if (i < NEDGE) {
    const int n0 = eI[i], n1 = eI[NEDGE + i];
    rcE[i] = (batch[n0] << 16) | (pos[n0] << 8) | pos[n1];
  } else if (i < 2 * NEDGE) {
    const int j = i - NEDGE;
    const int n0 = pI[j], n1 = pI[NEDGE + j];
    rcP[j] = (batch[n0] << 16) | (pos[n0] << 8) | pos[n1];
  } else if (i < 2 * NEDGE + NTOT) {
    const int j = i - 2 * NEDGE;
    rcN[j] = (batch[j] << 16) | (pos[j] << 8) | pos[j];
  }
}

// ---------------------------------------------------------------------------
// Mega kernel, 2048 blocks x 512 threads, PARITY-INTERLEAVED roles:
//   even blockIdx -> B-block: accumulate one (graph, h-quad) into 64 KB LDS,
//                    then write the 64x64 quadrant. LDS caps these at 2/CU.
//   odd  blockIdx -> Z-block: pure streaming zeros of the pad region
//                    (192 MiB total); no LDS, fills the other wave slots.
// Both roles are co-resident from t=0 -> store pipe continuously busy.
// ---------------------------------------------------------------------------
#define HQ  4
#define BT  512

__global__ __launch_bounds__(BT) void mega_kernel(
    const float* __restrict__ node_x, const float* __restrict__ loop_x,
    const float* __restrict__ edge_attr, const float* __restrict__ pair_x,
    const float* __restrict__ Wn, const float* __restrict__ Wl,
    const float* __restrict__ We, const float* __restrict__ Wp,
    const int* __restrict__ rcE, const int* __restrict__ rcP,
    const int* __restrict__ rcN, const int* __restrict__ counts,
    float* __restrict__ out, float* __restrict__ mask) {
  const int tid = threadIdx.x;
  const int d   = (int)blockIdx.x;

  if (d & 1) {
    // ================= Z-blocks: stream zeros (4 planes each) =============
    const int z = d >> 1;                   // 0..1023
#pragma unroll
    for (int t = 0; t < 4; ++t) {
      f4* plane = (f4*)(out + (size_t)(z * 4 + t) * (NMAXD * NMAXD));
      // rows 64-127 full width: f4 idx 2048..4095 (contiguous 32 KB)
#pragma unroll
      for (int k = 0; k < 4; ++k) plane[2048 + tid + k * BT] = (f4)(0.f);
      // rows 0-63, right half: idx r*32 + (16..31), 1024 f4
#pragma unroll
      for (int k = 0; k < 2; ++k) {
        const int i = tid + k * BT;
        plane[(i >> 4) * 32 + 16 + (i & 15)] = (f4)(0.f);
      }
    }
    return;
  }

  // ================= B-blocks: accumulate + quadrant write =================
  __shared__ float acc[HQ * 4096];           // 64 KB accumulator
  __shared__ f4 WcE[32];                     // W_edge[:, h0:h0+4]
  __shared__ f4 WcP[16];                     // W_pair[:, h0:h0+4]
  __shared__ f4 WcN[48];                     // [0:32)=W_node, [32:48)=W_loop

  // XCD-aware swizzle on the B-subgrid: all 16 hq-blocks of g on one XCD
  const int db = d >> 1;                     // 0..1023
  const int g  = ((db & 7) << 3) | ((db >> 3) & 7);
  const int h0 = (db >> 6) * HQ;

  if (tid < 32)       WcE[tid]            = *(const f4*)&We[tid * HD + h0];
  else if (tid < 48)  WcP[tid - 32]       = *(const f4*)&Wp[(tid - 32) * HD + h0];
  else if (tid < 80)  WcN[tid - 48]       = *(const f4*)&Wn[(tid - 48) * HD + h0];
  else if (tid < 96)  WcN[32 + tid - 80]  = *(const f4*)&Wl[(tid - 80) * HD + h0];
  for (int i = tid; i < HQ * 1024; i += BT) ((f4*)acc)[i] = (f4)(0.f);
  __syncthreads();

  // ---- edges (K=32): 2 items/thread, no dependent gathers ----
#pragma unroll
  for (int k = 0; k < 2; ++k) {
    const int j = g * EPG + tid + k * BT;
    const f4* xr = (const f4*)(edge_attr + (size_t)j * 32);
    f4 d4 = (f4)(0.f);
#pragma unroll
    for (int k4 = 0; k4 < 8; ++k4) {
      const f4 x = xr[k4];
#pragma unroll
      for (int u = 0; u < 4; ++u) d4 += x[u] * WcE[k4 * 4 + u];
    }
    const int code = rcE[j];
    const int b = code >> 16, r = (code >> 8) & 255, c = code & 255;
    if (b == g && r < 64 && c < 64) {
      const int a = r * 64 + c;
      atomicAdd(&acc[a], d4.x);          atomicAdd(&acc[4096 + a], d4.y);
      atomicAdd(&acc[8192 + a], d4.z);   atomicAdd(&acc[12288 + a], d4.w);
    } else {  // general fallback (never taken for this input layout)
      atomicAdd(&out[(((size_t)b * HD + h0 + 0) * NMAXD + r) * NMAXD + c], d4.x);
      atomicAdd(&out[(((size_t)b * HD + h0 + 1) * NMAXD + r) * NMAXD + c], d4.y);
      atomicAdd(&out[(((size_t)b * HD + h0 + 2) * NMAXD + r) * NMAXD + c], d4.z);
      atomicAdd(&out[(((size_t)b * HD + h0 + 3) * NMAXD + r) * NMAXD + c], d4.w);
    }
  }

  // ---- pairs (K=16): 2 items/thread ----
#pragma unroll
  for (int k = 0; k < 2; ++k) {
    const int j = g * EPG + tid + k * BT;
    const f4* xr = (const f4*)(pair_x + (size_t)j * 16);
    f4 d4 = (f4)(0.f);
#pragma unroll
    for (int k4 = 0; k4 < 4; ++k4) {
      const f4 x = xr[k4];
#pragma unroll
      for (int u = 0; u < 4; ++u) d4 += x[u] * WcP[k4 * 4 + u];
    }
    const int code = rcP[j];
    const int b = code >> 16, r = (code >> 8) & 255, c = code & 255;
    if (b == g && r < 64 && c < 64) {
      const int a = r * 64 + c;
      atomicAdd(&acc[a], d4.x);          atomicAdd(&acc[4096 + a], d4.y);
      atomicAdd(&acc[8192 + a], d4.z);   atomicAdd(&acc[12288 + a], d4.w);
    } else {
      atomicAdd(&out[(((size_t)b * HD + h0 + 0) * NMAXD + r) * NMAXD + c], d4.x);
      atomicAdd(&out[(((size_t)b * HD + h0 + 1) * NMAXD + r) * NMAXD + c], d4.y);
      atomicAdd(&out[(((size_t)b * HD + h0 + 2) * NMAXD + r) * NMAXD + c], d4.z);
      atomicAdd(&out[(((size_t)b * HD + h0 + 3) * NMAXD + r) * NMAXD + c], d4.w);
    }
  }

  // ---- nodes (K=48 = node_x 32 + loop_x 16), diagonal targets ----
  if (tid < NPG) {
    const int j = g * NPG + tid;
    const f4* xr = (const f4*)(node_x + (size_t)j * 32);
    const f4* lr = (const f4*)(loop_x + (size_t)j * 16);
    f4 d4 = (f4)(0.f);
#pragma unroll
    for (int k4 = 0; k4 < 8; ++k4) {
      const f4 x = xr[k4];
#pragma unroll
      for (int u = 0; u < 4; ++u) d4 += x[u] * WcN[k4 * 4 + u];
    }
#pragma unroll
    for (int k4 = 0; k4 < 4; ++k4) {
      const f4 x = lr[k4];
#pragma unroll
      for (int u = 0; u < 4; ++u) d4 += x[u] * WcN[32 + k4 * 4 + u];
    }
    const int code = rcN[j];
    const int b = code >> 16, r = (code >> 8) & 255, c = code & 255;
    if (b == g && r < 64 && c < 64) {
      const int a = r * 64 + c;
      atomicAdd(&acc[a], d4.x);          atomicAdd(&acc[4096 + a], d4.y);
      atomicAdd(&acc[8192 + a], d4.z);   atomicAdd(&acc[12288 + a], d4.w);
    } else {
      atomicAdd(&out[(((size_t)b * HD + h0 + 0) * NMAXD + r) * NMAXD + c], d4.x);
      atomicAdd(&out[(((size_t)b * HD + h0 + 1) * NMAXD + r) * NMAXD + c], d4.y);
      atomicAdd(&out[(((size_t)b * HD + h0 + 2) * NMAXD + r) * NMAXD + c], d4.z);
      atomicAdd(&out[(((size_t)b * HD + h0 + 3) * NMAXD + r) * NMAXD + c], d4.w);
    }
  }
  __syncthreads();

  // ---- write the 64x64 quadrant (rows 0-63, f4-cols 0-15) ----
#pragma unroll
  for (int t = 0; t < HQ; ++t) {
    f4* plane = (f4*)(out + ((size_t)g * HD + h0 + t) * NMAXD * NMAXD);
#pragma unroll
    for (int k = 0; k < 2; ++k) {
      const int idx = tid + k * BT;           // 0..1023
      const int r = idx >> 4, c4 = idx & 15;
      plane[r * 32 + c4] = *(const f4*)&acc[t * 4096 + r * 64 + c4 * 4];
    }
  }

  if (h0 == 0 && tid < NMAXD)
    mask[(size_t)g * NMAXD + tid] = (tid < counts[g]) ? 1.0f : 0.0f;
}

// ---------------------------------------------------------------------------
extern "C" void kernel_launch(void* const* d_in, const int* in_sizes, int n_in,
                              void* d_out, int out_size, void* d_ws, size_t ws_size,
                              hipStream_t stream) {
  const float* node_x    = (const float*)d_in[0];
  const float* loop_x    = (const float*)d_in[1];
  const float* edge_attr = (const float*)d_in[2];
  const float* pair_x    = (const float*)d_in[3];
  const float* W_node    = (const float*)d_in[4];
  const float* W_loop    = (const float*)d_in[5];
  const float* W_edge    = (const float*)d_in[6];
  const float* W_pair    = (const float*)d_in[7];
  const int*   batch     = (const int*)d_in[8];
  const int*   edge_index = (const int*)d_in[9];    // [2][E]
  const int*   pair_index = (const int*)d_in[10];   // [2][E]

  float* out  = (float*)d_out;
  float* mask = out + (size_t)NG * HD * NMAXD * NMAXD;

  // ws layout (int units): pos | starts | counts | rcE | rcP | rcN
  int* pos    = (int*)d_ws;
  int* starts = pos + NTOT;
  int* counts = starts + (NG + 1);
  int* rcE    = counts + NG;
  int* rcP    = rcE + NEDGE;
  int* rcN    = rcP + NEDGE;

  prep_kernel<<<1, 1024, 0, stream>>>(batch, starts, pos, counts);
  prep2_kernel<<<(2 * NEDGE + NTOT + 255) / 256, 256, 0, stream>>>(
      edge_index, pair_index, batch, pos, rcE, rcP, rcN);
  mega_kernel<<<2048, BT, 0, stream>>>(node_x, loop_x, edge_attr, pair_x,
      W_node, W_loop, W_edge, W_pair, rcE, rcP, rcN, counts, out, mask);
}

// Round 8
// 73.393 us; speedup vs baseline: 1.8876x; 1.8876x over previous
//
#include <hip/hip_runtime.h>

// Problem constants (from reference setup_inputs)
#define NTOT  4096    // total nodes
#define NG    64      // graphs (B)
#define NMAXD 128     // N_MAX dense padding
#define HD    64      // hidden dim
#define NEDGE 65536   // edges (and pairs)
#define EPG   (NEDGE / NG)   // 1024 edges per graph
#define NPG   (NTOT / NG)    // 64 nodes per graph

typedef float f4 __attribute__((ext_vector_type(4)));

// ---------------------------------------------------------------------------
// prep_all: one dependency-free kernel. Packed (b,r,c) codes for every
// edge/pair/node via per-item binary search on the sorted batch array
// (16 KB, L2-hot), plus counts[g]. No prior kernel needed.
// ---------------------------------------------------------------------------
__device__ __forceinline__ int lowb(const int* __restrict__ batch, int key) {
  int lo = 0, hi = NTOT;                    // first i with batch[i] >= key
  while (lo < hi) { const int mid = (lo + hi) >> 1;
    if (batch[mid] < key) lo = mid + 1; else hi = mid; }
  return lo;
}

__global__ __launch_bounds__(256) void prep_all_kernel(
    const int* __restrict__ eI, const int* __restrict__ pI,
    const int* __restrict__ batch,
    int* __restrict__ rcE, int* __restrict__ rcP, int* __restrict__ rcN,
    int* __restrict__ counts) {
  const int i = blockIdx.x * 256 + threadIdx.x;
  if (i < NEDGE) {
    const int n0 = eI[i], n1 = eI[NEDGE + i];
    const int b0 = batch[n0], b1 = batch[n1];
    rcE[i] = (b0 << 16) | ((n0 - lowb(batch, b0)) << 8) | (n1 - lowb(batch, b1));
  } else if (i < 2 * NEDGE) {
    const int j = i - NEDGE;
    const int n0 = pI[j], n1 = pI[NEDGE + j];
    const int b0 = batch[n0], b1 = batch[n1];
    rcP[j] = (b0 << 16) | ((n0 - lowb(batch, b0)) << 8) | (n1 - lowb(batch, b1));
  } else if (i < 2 * NEDGE + NTOT) {
    const int j = i - 2 * NEDGE;
    const int b = batch[j];
    const int p = j - lowb(batch, b);
    rcN[j] = (b << 16) | (p << 8) | p;
  } else if (i < 2 * NEDGE + NTOT + NG) {
    const int g = i - 2 * NEDGE - NTOT;
    counts[g] = lowb(batch, g + 1) - lowb(batch, g);
  }
}

// ---------------------------------------------------------------------------
// Fused encode + scatter + dense write, WAVE-SPECIALIZED (R5 structure).
// Block = (graph g, h-quad of 4). 512 threads (8 waves), 64 KB LDS -> 2/CU.
//   waves 4-7: stream the 192 KB zero region (no phase-1 dep) + mask
//   waves 0-3: on-the-fly projections + unsafeAtomicAdd (ds_add_f32) into LDS
//   barrier; all waves write the 64 KB quadrant.
// All atomics are unsafeAtomicAdd -> native HW FP atomics, no CAS loops.
// ---------------------------------------------------------------------------
#define HQ 4
#define SCT 512
__global__ __launch_bounds__(SCT) void fused_scatter_kernel(
    const float* __restrict__ node_x, const float* __restrict__ loop_x,
    const float* __restrict__ edge_attr, const float* __restrict__ pair_x,
    const float* __restrict__ Wn, const float* __restrict__ Wl,
    const float* __restrict__ We, const float* __restrict__ Wp,
    const int* __restrict__ rcE, const int* __restrict__ rcP,
    const int* __restrict__ rcN, const int* __restrict__ counts,
    float* __restrict__ out, float* __restrict__ mask) {
  __shared__ float acc[HQ * 4096];           // 64 KB accumulator
  __shared__ f4 WcE[32];                     // W_edge[:, h0:h0+4]
  __shared__ f4 WcP[16];                     // W_pair[:, h0:h0+4]
  __shared__ f4 WcN[48];                     // [0:32)=W_node, [32:48)=W_loop

  const int tid = threadIdx.x;
  // XCD-aware swizzle: all 16 hq-blocks of graph g on one XCD (d%8 rr)
  const int d  = (int)blockIdx.x;
  const int g  = ((d & 7) << 3) | ((d >> 3) & 7);
  const int h0 = (d >> 6) * HQ;

  if (tid < 32)       WcE[tid]            = *(const f4*)&We[tid * HD + h0];
  else if (tid < 48)  WcP[tid - 32]       = *(const f4*)&Wp[(tid - 32) * HD + h0];
  else if (tid < 80)  WcN[tid - 48]       = *(const f4*)&Wn[(tid - 48) * HD + h0];
  else if (tid < 96)  WcN[32 + tid - 80]  = *(const f4*)&Wl[(tid - 80) * HD + h0];
  for (int i = tid; i < HQ * 1024; i += SCT) ((f4*)acc)[i] = (f4)(0.f);
  __syncthreads();

  const int wid = tid >> 6;
  if (wid >= 4) {
    // ================= store waves: zero region (192 KB) =================
    const int tz = tid - 256;   // 0..255
#pragma unroll
    for (int t = 0; t < HQ; ++t) {
      f4* plane = (f4*)(out + ((size_t)g * HD + h0 + t) * NMAXD * NMAXD);
      // rows 0-63, f4-cols 16-31 (right half of top rows): 1024 f4
#pragma unroll
      for (int k = 0; k < 4; ++k) {
        const int idx = tz + k * 256;
        plane[(idx >> 4) * 32 + 16 + (idx & 15)] = (f4)(0.f);
      }
      // rows 64-127 full width: 2048 f4 (contiguous tail half of plane)
#pragma unroll
      for (int k = 0; k < 8; ++k)
        plane[2048 + tz + k * 256] = (f4)(0.f);
    }
    if (h0 == 0) {
      const int cg = counts[g];
      for (int i = tz; i < NMAXD; i += 256)
        mask[(size_t)g * NMAXD + i] = (i < cg) ? 1.0f : 0.0f;
    }
  } else {
    // ================= accumulate waves (lanes 0..255) =================
    // ---- edges (K=32): 4 items/thread ----
#pragma unroll
    for (int k = 0; k < 4; ++k) {
      const int j = g * EPG + tid + k * 256;
      const f4* xr = (const f4*)(edge_attr + (size_t)j * 32);
      f4 d4 = (f4)(0.f);
#pragma unroll
      for (int k4 = 0; k4 < 8; ++k4) {
        const f4 x = xr[k4];
#pragma unroll
        for (int u = 0; u < 4; ++u) d4 += x[u] * WcE[k4 * 4 + u];
      }
      const int code = rcE[j];
      const int b = code >> 16, r = (code >> 8) & 255, c = code & 255;
      if (b == g && r < 64 && c < 64) {
        const int a = r * 64 + c;
        unsafeAtomicAdd(&acc[a], d4.x);          unsafeAtomicAdd(&acc[4096 + a], d4.y);
        unsafeAtomicAdd(&acc[8192 + a], d4.z);   unsafeAtomicAdd(&acc[12288 + a], d4.w);
      } else {  // general fallback (never taken for this input layout)
        unsafeAtomicAdd(&out[(((size_t)b * HD + h0 + 0) * NMAXD + r) * NMAXD + c], d4.x);
        unsafeAtomicAdd(&out[(((size_t)b * HD + h0 + 1) * NMAXD + r) * NMAXD + c], d4.y);
        unsafeAtomicAdd(&out[(((size_t)b * HD + h0 + 2) * NMAXD + r) * NMAXD + c], d4.z);
        unsafeAtomicAdd(&out[(((size_t)b * HD + h0 + 3) * NMAXD + r) * NMAXD + c], d4.w);
      }
    }

    // ---- pairs (K=16): 4 items/thread ----
#pragma unroll
    for (int k = 0; k < 4; ++k) {
      const int j = g * EPG + tid + k * 256;
      const f4* xr = (const f4*)(pair_x + (size_t)j * 16);
      f4 d4 = (f4)(0.f);
#pragma unroll
      for (int k4 = 0; k4 < 4; ++k4) {
        const f4 x = xr[k4];
#pragma unroll
        for (int u = 0; u < 4; ++u) d4 += x[u] * WcP[k4 * 4 + u];
      }
      const int code = rcP[j];
      const int b = code >> 16, r = (code >> 8) & 255, c = code & 255;
      if (b == g && r < 64 && c < 64) {
        const int a = r * 64 + c;
        unsafeAtomicAdd(&acc[a], d4.x);          unsafeAtomicAdd(&acc[4096 + a], d4.y);
        unsafeAtomicAdd(&acc[8192 + a], d4.z);   unsafeAtomicAdd(&acc[12288 + a], d4.w);
      } else {
        unsafeAtomicAdd(&out[(((size_t)b * HD + h0 + 0) * NMAXD + r) * NMAXD + c], d4.x);
        unsafeAtomicAdd(&out[(((size_t)b * HD + h0 + 1) * NMAXD + r) * NMAXD + c], d4.y);
        unsafeAtomicAdd(&out[(((size_t)b * HD + h0 + 2) * NMAXD + r) * NMAXD + c], d4.z);
        unsafeAtomicAdd(&out[(((size_t)b * HD + h0 + 3) * NMAXD + r) * NMAXD + c], d4.w);
      }
    }

    // ---- nodes (K=48 = node_x 32 + loop_x 16), diagonal targets ----
    if (tid < NPG) {
      const int j = g * NPG + tid;
      const f4* xr = (const f4*)(node_x + (size_t)j * 32);
      const f4* lr = (const f4*)(loop_x + (size_t)j * 16);
      f4 d4 = (f4)(0.f);
#pragma unroll
      for (int k4 = 0; k4 < 8; ++k4) {
        const f4 x = xr[k4];
#pragma unroll
        for (int u = 0; u < 4; ++u) d4 += x[u] * WcN[k4 * 4 + u];
      }
#pragma unroll
      for (int k4 = 0; k4 < 4; ++k4) {
        const f4 x = lr[k4];
#pragma unroll
        for (int u = 0; u < 4; ++u) d4 += x[u] * WcN[32 + k4 * 4 + u];
      }
      const int code = rcN[j];
      const int b = code >> 16, r = (code >> 8) & 255, c = code & 255;
      if (b == g && r < 64 && c < 64) {
        const int a = r * 64 + c;
        unsafeAtomicAdd(&acc[a], d4.x);          unsafeAtomicAdd(&acc[4096 + a], d4.y);
        unsafeAtomicAdd(&acc[8192 + a], d4.z);   unsafeAtomicAdd(&acc[12288 + a], d4.w);
      } else {
        unsafeAtomicAdd(&out[(((size_t)b * HD + h0 + 0) * NMAXD + r) * NMAXD + c], d4.x);
        unsafeAtomicAdd(&out[(((size_t)b * HD + h0 + 1) * NMAXD + r) * NMAXD + c], d4.y);
        unsafeAtomicAdd(&out[(((size_t)b * HD + h0 + 2) * NMAXD + r) * NMAXD + c], d4.z);
        unsafeAtomicAdd(&out[(((size_t)b * HD + h0 + 3) * NMAXD + r) * NMAXD + c], d4.w);
      }
    }
  }
  __syncthreads();

  // ---- all waves: write the 64x64 quadrant (rows 0-63, f4-cols 0-15) ----
#pragma unroll
  for (int t = 0; t < HQ; ++t) {
    f4* plane = (f4*)(out + ((size_t)g * HD + h0 + t) * NMAXD * NMAXD);
#pragma unroll
    for (int k = 0; k < 2; ++k) {
      const int idx = tid + k * SCT;           // 0..1023
      const int r = idx >> 4, c4 = idx & 15;
      plane[r * 32 + c4] = *(const f4*)&acc[t * 4096 + r * 64 + c4 * 4];
    }
  }
}

// ---------------------------------------------------------------------------
extern "C" void kernel_launch(void* const* d_in, const int* in_sizes, int n_in,
                              void* d_out, int out_size, void* d_ws, size_t ws_size,
                              hipStream_t stream) {
  const float* node_x    = (const float*)d_in[0];
  const float* loop_x    = (const float*)d_in[1];
  const float* edge_attr = (const float*)d_in[2];
  const float* pair_x    = (const float*)d_in[3];
  const float* W_node    = (const float*)d_in[4];
  const float* W_loop    = (const float*)d_in[5];
  const float* W_edge    = (const float*)d_in[6];
  const float* W_pair    = (const float*)d_in[7];
  const int*   batch     = (const int*)d_in[8];
  const int*   edge_index = (const int*)d_in[9];    // [2][E]
  const int*   pair_index = (const int*)d_in[10];   // [2][E]

  float* out  = (float*)d_out;
  float* mask = out + (size_t)NG * HD * NMAXD * NMAXD;

  // ws layout (int units): rcE | rcP | rcN | counts
  int* rcE    = (int*)d_ws;
  int* rcP    = rcE + NEDGE;
  int* rcN    = rcP + NEDGE;
  int* counts = rcN + NTOT;

  const int prep_items = 2 * NEDGE + NTOT + NG;
  prep_all_kernel<<<(prep_items + 255) / 256, 256, 0, stream>>>(
      edge_index, pair_index, batch, rcE, rcP, rcN, counts);
  fused_scatter_kernel<<<NG * 16, SCT, 0, stream>>>(node_x, loop_x, edge_attr,
      pair_x, W_node, W_loop, W_edge, W_pair, rcE, rcP, rcN, counts, out, mask);
}